// Round 7
// baseline (411.007 us; speedup 1.0000x reference)
//
#include <hip/hip_runtime.h>

// TGV prox primal-dual, 30 iterations on (3,512,512) fp32.
// R7 structure: SINGLE-BARRIER kernel, no u-staging LDS.
// Falsified ladder: R4 bytes x0.6 -> -3.6% (not BW-bound); R5 occupancy x2 ->
// -3.2% (not slot-bound); R6 launches x0.53 -> 0% (not launch-overhead-bound).
// Remaining invariant: the in-kernel chain {stage u->LDS, barrier, stage-1
// loads, barrier, stage-2} with two exposed global-latency epochs. This
// version: tgather reads u (fp16) DIRECTLY from global (L1/L2 absorbs the
// ~3x halo overlap), all ~18 loads per thread issued upfront (one latency
// epoch); stage-2's u-old comes free from stage-1's center registers (same
// thread owns the strip in both stages); only ONE barrier (xbar/rbar LDS
// handoff); LDS 24->8.6 KB; block 192 (the 4th wave was always idle);
// rsqrt-based projections (1/max(n/l,1) == min(l*rsqrt(s),1), exact at the
// branch point; absmax headroom 0.0156 vs 0.0813).
// State: x2 fp32 + r/u fp16 ping-pong (verified R4/R5). 30 launches (R6
// showed fusion is neutral). R3: grid.sync costs ~200us/iter -> never again.

#define H 512
#define W 512
#define C 3
#define HW (H * W)
#define CHW (C * H * W)
#define N_IT 30

#define TW 64
#define TH 8

#define TAU     0.01f
#define LAM2    0.15f
#define RHO     1.99f
#define SIGMA   1.3888888888888888f   /* 1/TAU/72 */
#define TL1     0.001f                /* TAU*LAM1 */
#define INV_1PT (1.0f / 1.01f)        /* 1/(1+TAU) */

// xbar/rbar planes rows -1..8 (10), cols lc = col+4 (col -4..67)
#define BROWS 10
#define BSTR  72

typedef _Float16 f16;
typedef __attribute__((ext_vector_type(4))) _Float16 h4;

// fp16 state plane order within an h-buffer: 0=r0 1=r1 2..5=u0..u3
#define HP_R0 0
#define HP_R1 1
#define HP_U  2

template <int MODE> // 0 = first iter, 1 = middle, 2 = last (dst = d_out interleaved)
__global__ __launch_bounds__(192)
void fused_it(const float* __restrict__ y,
              const float* __restrict__ srcX,
              const f16*   __restrict__ srcH,
              float*       __restrict__ dstX,
              f16*         __restrict__ dstH,
              float*       __restrict__ outp)
{
    __shared__ float sb[3][BROWS][BSTR]; // 0=xbar 1=rbar0 2=rbar1

    const int tid = threadIdx.x;
    const int c   = blockIdx.z;
    const int i0  = blockIdx.y * TH;
    const int j0  = blockIdx.x * TW;
    const int cb  = c * HW;

    const f16* pu0 = srcH + (HP_U + 0) * CHW + cb;
    const f16* pu1 = srcH + (HP_U + 1) * CHW + cb;
    const f16* pu2 = srcH + (HP_U + 2) * CHW + cb;
    const f16* pu3 = srcH + (HP_U + 3) * CHW + cb;

    // masked u loads replicating the old zero-padded LDS semantics:
    // value if inside the image, else 0.
    auto ld4 = [&](const f16* p, int gi_, int gj_) -> h4 {
        h4 z = {};
        if ((unsigned)gi_ < H && gj_ >= 0 && gj_ + 3 < W)
            z = *(const h4*)(p + gi_ * W + gj_);
        return z;
    };
    auto ld1 = [&](const f16* p, int gi_, int gj_) -> float {
        return ((unsigned)gi_ < H && (unsigned)gj_ < W) ? (float)p[gi_ * W + gj_] : 0.f;
    };

    // center-u kept in registers for stage-2 (valid for interior threads)
    float cu0[4], cu1[4], cu2[4], cu3[4];

    // ---- stage 1: x/r prox on a strip of 4 positions; xbar/rbar -> LDS ----
    auto strip1 = [&](int rr, int s, bool interior) {
        const int gi  = i0 + rr;
        const int gjb = j0 + s;
        const bool row_ok = (unsigned)gi < H;

        float yv[4], x2c[4], r0c[4], r1c[4];
        if (row_ok && gjb >= 0 && gjb + 3 < W) {
            const int p = cb + gi * W + gjb;
            *(float4*)yv = *(const float4*)(y + p);
            if (MODE != 0) {
                *(float4*)x2c = *(const float4*)(srcX + p);
                h4 h0 = *(const h4*)(srcH + HP_R0 * CHW + p);
                h4 h1 = *(const h4*)(srcH + HP_R1 * CHW + p);
                #pragma unroll
                for (int e = 0; e < 4; ++e) { r0c[e] = (float)h0[e]; r1c[e] = (float)h1[e]; }
            }
        } else {
            #pragma unroll
            for (int e = 0; e < 4; ++e) {
                const int gj = gjb + e;
                const bool ok = row_ok && ((unsigned)gj < W);
                const int p = cb + gi * W + gj;
                yv[e] = ok ? y[p] : 0.f;
                if (MODE != 0) {
                    x2c[e] = ok ? srcX[p] : 0.f;
                    r0c[e] = ok ? (float)srcH[HP_R0 * CHW + p] : 0.f;
                    r1c[e] = ok ? (float)srcH[HP_R1 * CHW + p] : 0.f;
                }
            }
        }

        float t0c[4], t1c[4], t0n[4], t1w[4];
        if (MODE == 0) {
            #pragma unroll
            for (int e = 0; e < 4; ++e) {
                x2c[e] = yv[e]; r0c[e] = 0.f; r1c[e] = 0.f;
                t0c[e] = t1c[e] = t0n[e] = t1w[e] = 0.f;
            }
            if (interior) {
                #pragma unroll
                for (int e = 0; e < 4; ++e) { cu0[e] = cu1[e] = cu2[e] = cu3[e] = 0.f; }
            }
        } else {
            // direct-from-global tgather (all loads independent -> one vmcnt epoch)
            float u0n[4], u0c[4], u0s[4], u1n[5], u1c[5], u2r[6], u3n[5], u3c[5];
            h4 v;
            v = ld4(pu0, gi - 1, gjb); u0n[0]=v[0]; u0n[1]=v[1]; u0n[2]=v[2]; u0n[3]=v[3];
            v = ld4(pu0, gi,     gjb); u0c[0]=v[0]; u0c[1]=v[1]; u0c[2]=v[2]; u0c[3]=v[3];
            v = ld4(pu0, gi + 1, gjb); u0s[0]=v[0]; u0s[1]=v[1]; u0s[2]=v[2]; u0s[3]=v[3];
            v = ld4(pu1, gi - 1, gjb); u1n[0]=v[0]; u1n[1]=v[1]; u1n[2]=v[2]; u1n[3]=v[3];
            u1n[4] = ld1(pu1, gi - 1, gjb + 4);
            v = ld4(pu1, gi,     gjb); u1c[0]=v[0]; u1c[1]=v[1]; u1c[2]=v[2]; u1c[3]=v[3];
            u1c[4] = ld1(pu1, gi, gjb + 4);
            u2r[0] = ld1(pu2, gi, gjb - 1);
            v = ld4(pu2, gi,     gjb); u2r[1]=v[0]; u2r[2]=v[1]; u2r[3]=v[2]; u2r[4]=v[3];
            u2r[5] = ld1(pu2, gi, gjb + 4);
            u3n[0] = ld1(pu3, gi - 1, gjb - 1);
            v = ld4(pu3, gi - 1, gjb); u3n[1]=v[0]; u3n[2]=v[1]; u3n[3]=v[2]; u3n[4]=v[3];
            u3c[0] = ld1(pu3, gi, gjb - 1);
            v = ld4(pu3, gi,     gjb); u3c[1]=v[0]; u3c[2]=v[1]; u3c[3]=v[2]; u3c[4]=v[3];

            const bool im0 = gi > 0, imHl = gi < H - 1;
            #pragma unroll
            for (int e = 0; e < 4; ++e) {
                const int gj = gjb + e;
                const bool jm0 = gj > 0;
                t0c[e] = TAU * (u0c[e] - u0s[e] + (jm0 ? u1c[e] : 0.f) - u1c[e + 1]);
                t1c[e] = TAU * (u2r[e + 1] - u2r[e + 2] + u3n[e + 1] - (imHl ? u3c[e + 1] : 0.f));
                t0n[e] = im0 ? TAU * (u0n[e] - u0c[e] + (jm0 ? u1n[e] : 0.f) - u1n[e + 1]) : 0.f;
                t1w[e] = jm0 ? TAU * (u2r[e] - u2r[e + 1] + u3n[e] - (imHl ? u3c[e] : 0.f)) : 0.f;
            }
            if (interior) {
                // stage-2's u-old at the center = these exact values: keep in regs
                #pragma unroll
                for (int e = 0; e < 4; ++e) {
                    cu0[e] = u0c[e]; cu1[e] = u1c[e];
                    cu2[e] = u2r[e + 1]; cu3[e] = u3c[e + 1];
                }
            }
        }

        const bool imH = gi < H - 1;
        float xnew[4], rn0[4], rn1[4], xb[4], rb0[4], rb1[4];
        #pragma unroll
        for (int e = 0; e < 4; ++e) {
            const int gj = gjb + e;
            const bool jmW = gj < W - 1;
            const float nT  = t0n[e] - (imH ? t0c[e] : 0.f) + t1w[e] - (jmW ? t1c[e] : 0.f);
            const float xv  = (x2c[e] - nT + TAU * yv[e]) * INV_1PT;
            xb[e] = 2.f * xv - x2c[e];
            const float rp0 = r0c[e] + t0c[e];
            const float rp1 = r1c[e] + t1c[e];
            const float ss  = rp0 * rp0 + rp1 * rp1;
            // f = 1 - 1/max(nrm/ (TAU*LAM1), 1) == 1 - min(TL1*rsqrt(ss), 1)
            const float f   = 1.f - fminf(TL1 * rsqrtf(ss), 1.f);
            const float rv0 = rp0 * f, rv1 = rp1 * f;
            rb0[e]  = 2.f * rv0 - r0c[e];
            rb1[e]  = 2.f * rv1 - r1c[e];
            xnew[e] = x2c[e] + RHO * (xv - x2c[e]);
            rn0[e]  = r0c[e] + RHO * (rv0 - r0c[e]);
            rn1[e]  = r1c[e] + RHO * (rv1 - r1c[e]);
        }
        *(float4*)&sb[0][rr + 1][s + 4] = *(float4*)xb;
        *(float4*)&sb[1][rr + 1][s + 4] = *(float4*)rb0;
        *(float4*)&sb[2][rr + 1][s + 4] = *(float4*)rb1;

        if (interior) {
            const int p = cb + gi * W + gjb;
            if (MODE == 2) {
                *(float4*)(outp + p) = *(float4*)xnew;
                *(float4*)(outp + CHW + 2 * p)     = make_float4(rn0[0], rn1[0], rn0[1], rn1[1]);
                *(float4*)(outp + CHW + 2 * p + 4) = make_float4(rn0[2], rn1[2], rn0[3], rn1[3]);
            } else {
                *(float4*)(dstX + p) = *(float4*)xnew;
                h4 h0, h1;
                #pragma unroll
                for (int e = 0; e < 4; ++e) { h0[e] = (f16)rn0[e]; h1[e] = (f16)rn1[e]; }
                *(h4*)(dstH + HP_R0 * CHW + p) = h0;
                *(h4*)(dstH + HP_R1 * CHW + p) = h1;
            }
        }
    };

    // stage 1, all concurrent: threads 0-127 interior (8 rows x 16 strips),
    // threads 128-179 the 52 ring strips (different waves -> true overlap)
    if (tid < 128) {
        strip1(tid >> 4, 4 * (tid & 15), true);
    } else if (tid < 180) {
        const int t = tid - 128;
        int rr, s;
        if (t < 18)      { rr = -1;      s = 4 * t - 4; }
        else if (t < 36) { rr = TH;      s = 4 * (t - 18) - 4; }
        else if (t < 44) { rr = t - 36;  s = -4; }
        else             { rr = t - 44;  s = TW; }
        strip1(rr, s, false);
    }
    __syncthreads(); // the ONLY barrier: xbar/rbar handoff

    // ---- stage 2: u prox on interior; u-old from registers ----
    if (tid < 128) {
        const int tx = tid & 15, ty = tid >> 4;
        const int gi  = i0 + ty;
        const int gjb = j0 + 4 * tx;
        const int lr  = ty + 1;
        const int lc  = 4 * tx + 4;
        float4 v;
        float xA[6], xS[6], xN[4], r0C[5], r0N[4], r1C[5], r1S[4];
        xA[0] = sb[0][lr][lc - 1];
        v = *(const float4*)&sb[0][lr][lc]; xA[1]=v.x; xA[2]=v.y; xA[3]=v.z; xA[4]=v.w;
        xA[5] = sb[0][lr][lc + 4];
        xS[0] = sb[0][lr + 1][lc - 1];
        v = *(const float4*)&sb[0][lr + 1][lc]; xS[1]=v.x; xS[2]=v.y; xS[3]=v.z; xS[4]=v.w;
        xS[5] = sb[0][lr + 1][lc + 4];
        v = *(const float4*)&sb[0][lr - 1][lc]; xN[0]=v.x; xN[1]=v.y; xN[2]=v.z; xN[3]=v.w;
        r0C[0] = sb[1][lr][lc - 1];
        v = *(const float4*)&sb[1][lr][lc]; r0C[1]=v.x; r0C[2]=v.y; r0C[3]=v.z; r0C[4]=v.w;
        v = *(const float4*)&sb[1][lr - 1][lc]; r0N[0]=v.x; r0N[1]=v.y; r0N[2]=v.z; r0N[3]=v.w;
        r1C[0] = sb[2][lr][lc - 1];
        v = *(const float4*)&sb[2][lr][lc]; r1C[1]=v.x; r1C[2]=v.y; r1C[3]=v.z; r1C[4]=v.w;
        v = *(const float4*)&sb[2][lr + 1][lc]; r1S[0]=v.x; r1S[1]=v.y; r1S[2]=v.z; r1S[3]=v.w;

        const bool im0 = gi > 0, imH = gi < H - 1;
        float un0[4], un1[4], un2[4], un3[4];
        #pragma unroll
        for (int e = 0; e < 4; ++e) {
            const int gj = gjb + e;
            const bool jm0 = gj > 0, jmW = gj < W - 1;
            const float xC = xA[e + 1], xE = xA[e + 2], xW_ = xA[e];
            const float I0c = (imH ? xS[e + 1] - xC : 0.f) - r0C[e + 1];
            const float I0n = im0 ? (xC - xN[e] - r0N[e]) : 0.f;
            const float I0w = jm0 ? ((imH ? xS[e] - xW_ : 0.f) - r0C[e]) : 0.f;
            const float I1c = (jmW ? xE - xC : 0.f) - r1C[e + 1];
            const float I1w = jm0 ? (xC - xW_ - r1C[e]) : 0.f;
            const float I1s = imH ? ((jmW ? xS[e + 2] - xS[e + 1] : 0.f) - r1S[e]) : 0.f;
            const float g0 = I0c - I0n;
            const float g1 = jm0 ? (I0c - I0w) : 0.f;
            const float g2 = I1c - I1w;
            const float g3 = imH ? (I1s - I1c) : 0.f;
            const float up0 = cu0[e] + SIGMA * g0;
            const float up1 = cu1[e] + SIGMA * g1;
            const float up2 = cu2[e] + SIGMA * g2;
            const float up3 = cu3[e] + SIGMA * g3;
            const float ss  = up0 * up0 + up1 * up1 + up2 * up2 + up3 * up3;
            // inv = 1/max(nrm/LAM2, 1) == min(LAM2*rsqrt(ss), 1)
            const float inv = fminf(LAM2 * rsqrtf(ss), 1.f);
            un0[e] = cu0[e] + RHO * (up0 * inv - cu0[e]);
            un1[e] = cu1[e] + RHO * (up1 * inv - cu1[e]);
            un2[e] = cu2[e] + RHO * (up2 * inv - cu2[e]);
            un3[e] = cu3[e] + RHO * (up3 * inv - cu3[e]);
        }
        const int p = cb + gi * W + gjb;
        if (MODE == 2) {
            #pragma unroll
            for (int e = 0; e < 4; ++e)
                *(float4*)(outp + 3 * CHW + 4 * (p + e)) =
                    make_float4(un0[e], un1[e], un2[e], un3[e]);
        } else {
            h4 o0, o1, o2, o3;
            #pragma unroll
            for (int e = 0; e < 4; ++e) {
                o0[e] = (f16)un0[e]; o1[e] = (f16)un1[e];
                o2[e] = (f16)un2[e]; o3[e] = (f16)un3[e];
            }
            *(h4*)(dstH + (HP_U + 0) * CHW + p) = o0;
            *(h4*)(dstH + (HP_U + 1) * CHW + p) = o1;
            *(h4*)(dstH + (HP_U + 2) * CHW + p) = o2;
            *(h4*)(dstH + (HP_U + 3) * CHW + p) = o3;
        }
    }
}

extern "C" void kernel_launch(void* const* d_in, const int* in_sizes, int n_in,
                              void* d_out, int out_size, void* d_ws, size_t ws_size,
                              hipStream_t stream) {
    const float* y = (const float*)d_in[0];
    float* out = (float*)d_out;

    // ws layout: x2 fp32 buf0 | x2 fp32 buf1 | h-buf0 (6*CHW f16) | h-buf1
    float* x0 = (float*)d_ws;
    float* x1 = x0 + CHW;
    f16*   h0 = (f16*)(x1 + CHW);
    f16*   h1 = h0 + 6 * CHW;

    dim3 blk(192, 1, 1);
    dim3 grd(W / TW, H / TH, C);    // (8, 64, 3) = 1536 blocks

    fused_it<0><<<grd, blk, 0, stream>>>(y, nullptr, nullptr, x0, h0, nullptr);
    for (int k = 2; k < N_IT; ++k) {
        const bool even = (k % 2 == 0);
        float* sx = even ? x0 : x1;  f16* sh = even ? h0 : h1;
        float* dx = even ? x1 : x0;  f16* dh = even ? h1 : h0;
        fused_it<1><<<grd, blk, 0, stream>>>(y, sx, sh, dx, dh, nullptr);
    }
    fused_it<2><<<grd, blk, 0, stream>>>(y, x0, h0, nullptr, nullptr, out);
}

// Round 8
// 383.684 us; speedup vs baseline: 1.0712x; 1.0712x over previous
//
#include <hip/hip_runtime.h>
#include <type_traits>

// TGV prox primal-dual, 30 iterations on (3,512,512) fp32.
// R8: BLOCK-UNIFORM INTERIOR FAST PATH (single variable vs R7).
// Falsified ladder: R4 bytes x0.6 -> -3.6%; R5 occupancy x2 -> -3.2%;
// R6 launches x0.53 -> 0%; R7 epochs/barriers halved -> 0%. The invariant
// across all: per-thread instruction stream (masked loads + boundary
// ternaries). R3's real-kernel PMC implies ~4.7us/iter pure VALU issue ->
// issue+dep-ALU is the remaining candidate for the ~13.5us/iter floor.
// 72.7% of blocks (bx in [1,6], by in [1,62]) have ALL accesses provably
// in-image and ALL boundary conds true -> scalar-branch to a mask-free body
// (unconditional vector loads, ternary-free t/nT/I terms). Bit-identical
// results. Edge blocks + MODE 0 run R7's exact path.
// State: x2 fp32 + r/u fp16 ping-pong; single barrier; block 192; rsqrt
// projections; 30 launches. R3: never grid.sync on this chip (~200us/iter).

#define H 512
#define W 512
#define C 3
#define HW (H * W)
#define CHW (C * H * W)
#define N_IT 30

#define TW 64
#define TH 8

#define TAU     0.01f
#define LAM2    0.15f
#define RHO     1.99f
#define SIGMA   1.3888888888888888f   /* 1/TAU/72 */
#define TL1     0.001f                /* TAU*LAM1 */
#define INV_1PT (1.0f / 1.01f)        /* 1/(1+TAU) */

// xbar/rbar planes rows -1..8 (10), cols lc = col+4 (col -4..67)
#define BROWS 10
#define BSTR  72

typedef _Float16 f16;
typedef __attribute__((ext_vector_type(4))) _Float16 h4;

// fp16 state plane order within an h-buffer: 0=r0 1=r1 2..5=u0..u3
#define HP_R0 0
#define HP_R1 1
#define HP_U  2

template <int MODE> // 0 = first iter, 1 = middle, 2 = last (dst = d_out interleaved)
__global__ __launch_bounds__(192)
void fused_it(const float* __restrict__ y,
              const float* __restrict__ srcX,
              const f16*   __restrict__ srcH,
              float*       __restrict__ dstX,
              f16*         __restrict__ dstH,
              float*       __restrict__ outp)
{
    __shared__ float sb[3][BROWS][BSTR]; // 0=xbar 1=rbar0 2=rbar1

    const int tid = threadIdx.x;
    const int c   = blockIdx.z;
    const int i0  = blockIdx.y * TH;
    const int j0  = blockIdx.x * TW;
    const int cb  = c * HW;

    // block-uniform: all halo accesses in-image and all boundary conds true?
    const bool edge = (MODE == 0) ||
                      (blockIdx.x == 0) || (blockIdx.x == W / TW - 1) ||
                      (blockIdx.y == 0) || (blockIdx.y == H / TH - 1);

    const f16* pu0 = srcH + (HP_U + 0) * CHW + cb;
    const f16* pu1 = srcH + (HP_U + 1) * CHW + cb;
    const f16* pu2 = srcH + (HP_U + 2) * CHW + cb;
    const f16* pu3 = srcH + (HP_U + 3) * CHW + cb;

    auto ld4 = [&](const f16* p, int gi_, int gj_) -> h4 {
        h4 z = {};
        if ((unsigned)gi_ < H && gj_ >= 0 && gj_ + 3 < W)
            z = *(const h4*)(p + gi_ * W + gj_);
        return z;
    };
    auto ld1 = [&](const f16* p, int gi_, int gj_) -> float {
        return ((unsigned)gi_ < H && (unsigned)gj_ < W) ? (float)p[gi_ * W + gj_] : 0.f;
    };

    // center-u kept in registers for stage-2 (valid for interior threads)
    float cu0[4], cu1[4], cu2[4], cu3[4];

    // ---- stage 1: x/r prox on a strip of 4 positions; xbar/rbar -> LDS ----
    // SAFE=true: block-uniform mask-free body (bit-identical to masked body).
    auto strip1 = [&](auto SAFE_c, int rr, int s, bool interior) {
        constexpr bool SAFE = decltype(SAFE_c)::value;
        const int gi  = i0 + rr;
        const int gjb = j0 + s;

        float yv[4], x2c[4], r0c[4], r1c[4];
        float t0c[4], t1c[4], t0n[4], t1w[4];

        if constexpr (SAFE) {
            const int p = cb + gi * W + gjb;
            *(float4*)yv  = *(const float4*)(y + p);
            *(float4*)x2c = *(const float4*)(srcX + p);
            h4 h0 = *(const h4*)(srcH + HP_R0 * CHW + p);
            h4 h1 = *(const h4*)(srcH + HP_R1 * CHW + p);
            #pragma unroll
            for (int e = 0; e < 4; ++e) { r0c[e] = (float)h0[e]; r1c[e] = (float)h1[e]; }

            float u0n[4], u0c[4], u0s[4], u1n[5], u1c[5], u2r[6], u3n[5], u3c[5];
            h4 v;
            const int rN = (gi - 1) * W + gjb, rC = gi * W + gjb, rS = (gi + 1) * W + gjb;
            v = *(const h4*)(pu0 + rN); u0n[0]=v[0]; u0n[1]=v[1]; u0n[2]=v[2]; u0n[3]=v[3];
            v = *(const h4*)(pu0 + rC); u0c[0]=v[0]; u0c[1]=v[1]; u0c[2]=v[2]; u0c[3]=v[3];
            v = *(const h4*)(pu0 + rS); u0s[0]=v[0]; u0s[1]=v[1]; u0s[2]=v[2]; u0s[3]=v[3];
            v = *(const h4*)(pu1 + rN); u1n[0]=v[0]; u1n[1]=v[1]; u1n[2]=v[2]; u1n[3]=v[3];
            u1n[4] = (float)pu1[rN + 4];
            v = *(const h4*)(pu1 + rC); u1c[0]=v[0]; u1c[1]=v[1]; u1c[2]=v[2]; u1c[3]=v[3];
            u1c[4] = (float)pu1[rC + 4];
            u2r[0] = (float)pu2[rC - 1];
            v = *(const h4*)(pu2 + rC); u2r[1]=v[0]; u2r[2]=v[1]; u2r[3]=v[2]; u2r[4]=v[3];
            u2r[5] = (float)pu2[rC + 4];
            u3n[0] = (float)pu3[rN - 1];
            v = *(const h4*)(pu3 + rN); u3n[1]=v[0]; u3n[2]=v[1]; u3n[3]=v[2]; u3n[4]=v[3];
            u3c[0] = (float)pu3[rC - 1];
            v = *(const h4*)(pu3 + rC); u3c[1]=v[0]; u3c[2]=v[1]; u3c[3]=v[2]; u3c[4]=v[3];

            #pragma unroll
            for (int e = 0; e < 4; ++e) {
                t0c[e] = TAU * (u0c[e] - u0s[e] + u1c[e] - u1c[e + 1]);
                t1c[e] = TAU * (u2r[e + 1] - u2r[e + 2] + u3n[e + 1] - u3c[e + 1]);
                t0n[e] = TAU * (u0n[e] - u0c[e] + u1n[e] - u1n[e + 1]);
                t1w[e] = TAU * (u2r[e] - u2r[e + 1] + u3n[e] - u3c[e]);
            }
            if (interior) {
                #pragma unroll
                for (int e = 0; e < 4; ++e) {
                    cu0[e] = u0c[e]; cu1[e] = u1c[e];
                    cu2[e] = u2r[e + 1]; cu3[e] = u3c[e + 1];
                }
            }
        } else {
            const bool row_ok = (unsigned)gi < H;
            if (row_ok && gjb >= 0 && gjb + 3 < W) {
                const int p = cb + gi * W + gjb;
                *(float4*)yv = *(const float4*)(y + p);
                if (MODE != 0) {
                    *(float4*)x2c = *(const float4*)(srcX + p);
                    h4 h0 = *(const h4*)(srcH + HP_R0 * CHW + p);
                    h4 h1 = *(const h4*)(srcH + HP_R1 * CHW + p);
                    #pragma unroll
                    for (int e = 0; e < 4; ++e) { r0c[e] = (float)h0[e]; r1c[e] = (float)h1[e]; }
                }
            } else {
                #pragma unroll
                for (int e = 0; e < 4; ++e) {
                    const int gj = gjb + e;
                    const bool ok = row_ok && ((unsigned)gj < W);
                    const int p = cb + gi * W + gj;
                    yv[e] = ok ? y[p] : 0.f;
                    if (MODE != 0) {
                        x2c[e] = ok ? srcX[p] : 0.f;
                        r0c[e] = ok ? (float)srcH[HP_R0 * CHW + p] : 0.f;
                        r1c[e] = ok ? (float)srcH[HP_R1 * CHW + p] : 0.f;
                    }
                }
            }
            if (MODE == 0) {
                #pragma unroll
                for (int e = 0; e < 4; ++e) {
                    x2c[e] = yv[e]; r0c[e] = 0.f; r1c[e] = 0.f;
                    t0c[e] = t1c[e] = t0n[e] = t1w[e] = 0.f;
                }
                if (interior) {
                    #pragma unroll
                    for (int e = 0; e < 4; ++e) { cu0[e] = cu1[e] = cu2[e] = cu3[e] = 0.f; }
                }
            } else {
                float u0n[4], u0c[4], u0s[4], u1n[5], u1c[5], u2r[6], u3n[5], u3c[5];
                h4 v;
                v = ld4(pu0, gi - 1, gjb); u0n[0]=v[0]; u0n[1]=v[1]; u0n[2]=v[2]; u0n[3]=v[3];
                v = ld4(pu0, gi,     gjb); u0c[0]=v[0]; u0c[1]=v[1]; u0c[2]=v[2]; u0c[3]=v[3];
                v = ld4(pu0, gi + 1, gjb); u0s[0]=v[0]; u0s[1]=v[1]; u0s[2]=v[2]; u0s[3]=v[3];
                v = ld4(pu1, gi - 1, gjb); u1n[0]=v[0]; u1n[1]=v[1]; u1n[2]=v[2]; u1n[3]=v[3];
                u1n[4] = ld1(pu1, gi - 1, gjb + 4);
                v = ld4(pu1, gi,     gjb); u1c[0]=v[0]; u1c[1]=v[1]; u1c[2]=v[2]; u1c[3]=v[3];
                u1c[4] = ld1(pu1, gi, gjb + 4);
                u2r[0] = ld1(pu2, gi, gjb - 1);
                v = ld4(pu2, gi,     gjb); u2r[1]=v[0]; u2r[2]=v[1]; u2r[3]=v[2]; u2r[4]=v[3];
                u2r[5] = ld1(pu2, gi, gjb + 4);
                u3n[0] = ld1(pu3, gi - 1, gjb - 1);
                v = ld4(pu3, gi - 1, gjb); u3n[1]=v[0]; u3n[2]=v[1]; u3n[3]=v[2]; u3n[4]=v[3];
                u3c[0] = ld1(pu3, gi, gjb - 1);
                v = ld4(pu3, gi,     gjb); u3c[1]=v[0]; u3c[2]=v[1]; u3c[3]=v[2]; u3c[4]=v[3];

                const bool im0 = gi > 0, imHl = gi < H - 1;
                #pragma unroll
                for (int e = 0; e < 4; ++e) {
                    const int gj = gjb + e;
                    const bool jm0 = gj > 0;
                    t0c[e] = TAU * (u0c[e] - u0s[e] + (jm0 ? u1c[e] : 0.f) - u1c[e + 1]);
                    t1c[e] = TAU * (u2r[e + 1] - u2r[e + 2] + u3n[e + 1] - (imHl ? u3c[e + 1] : 0.f));
                    t0n[e] = im0 ? TAU * (u0n[e] - u0c[e] + (jm0 ? u1n[e] : 0.f) - u1n[e + 1]) : 0.f;
                    t1w[e] = jm0 ? TAU * (u2r[e] - u2r[e + 1] + u3n[e] - (imHl ? u3c[e] : 0.f)) : 0.f;
                }
                if (interior) {
                    #pragma unroll
                    for (int e = 0; e < 4; ++e) {
                        cu0[e] = u0c[e]; cu1[e] = u1c[e];
                        cu2[e] = u2r[e + 1]; cu3[e] = u3c[e + 1];
                    }
                }
            }
        }

        float xnew[4], rn0[4], rn1[4], xb[4], rb0[4], rb1[4];
        {
            const bool imH = SAFE ? true : (gi < H - 1);
            #pragma unroll
            for (int e = 0; e < 4; ++e) {
                const int gj = gjb + e;
                const bool jmW = SAFE ? true : (gj < W - 1);
                const float nT  = t0n[e] - (imH ? t0c[e] : 0.f) + t1w[e] - (jmW ? t1c[e] : 0.f);
                const float xv  = (x2c[e] - nT + TAU * yv[e]) * INV_1PT;
                xb[e] = 2.f * xv - x2c[e];
                const float rp0 = r0c[e] + t0c[e];
                const float rp1 = r1c[e] + t1c[e];
                const float ss  = rp0 * rp0 + rp1 * rp1;
                const float f   = 1.f - fminf(TL1 * rsqrtf(ss), 1.f);
                const float rv0 = rp0 * f, rv1 = rp1 * f;
                rb0[e]  = 2.f * rv0 - r0c[e];
                rb1[e]  = 2.f * rv1 - r1c[e];
                xnew[e] = x2c[e] + RHO * (xv - x2c[e]);
                rn0[e]  = r0c[e] + RHO * (rv0 - r0c[e]);
                rn1[e]  = r1c[e] + RHO * (rv1 - r1c[e]);
            }
        }
        *(float4*)&sb[0][rr + 1][s + 4] = *(float4*)xb;
        *(float4*)&sb[1][rr + 1][s + 4] = *(float4*)rb0;
        *(float4*)&sb[2][rr + 1][s + 4] = *(float4*)rb1;

        if (interior) {
            const int p = cb + gi * W + gjb;
            if (MODE == 2) {
                *(float4*)(outp + p) = *(float4*)xnew;
                *(float4*)(outp + CHW + 2 * p)     = make_float4(rn0[0], rn1[0], rn0[1], rn1[1]);
                *(float4*)(outp + CHW + 2 * p + 4) = make_float4(rn0[2], rn1[2], rn0[3], rn1[3]);
            } else {
                *(float4*)(dstX + p) = *(float4*)xnew;
                h4 h0, h1;
                #pragma unroll
                for (int e = 0; e < 4; ++e) { h0[e] = (f16)rn0[e]; h1[e] = (f16)rn1[e]; }
                *(h4*)(dstH + HP_R0 * CHW + p) = h0;
                *(h4*)(dstH + HP_R1 * CHW + p) = h1;
            }
        }
    };

    auto ringmap = [&](int t, int& rr, int& s) {
        if (t < 18)      { rr = -1;      s = 4 * t - 4; }
        else if (t < 36) { rr = TH;      s = 4 * (t - 18) - 4; }
        else if (t < 44) { rr = t - 36;  s = -4; }
        else             { rr = t - 44;  s = TW; }
    };

    if (!edge) {
        if (tid < 128) {
            strip1(std::true_type{}, tid >> 4, 4 * (tid & 15), true);
        } else if (tid < 180) {
            int rr, s; ringmap(tid - 128, rr, s);
            strip1(std::true_type{}, rr, s, false);
        }
    } else {
        if (tid < 128) {
            strip1(std::false_type{}, tid >> 4, 4 * (tid & 15), true);
        } else if (tid < 180) {
            int rr, s; ringmap(tid - 128, rr, s);
            strip1(std::false_type{}, rr, s, false);
        }
    }
    __syncthreads(); // the ONLY barrier: xbar/rbar handoff

    // ---- stage 2: u prox on interior; u-old from registers ----
    auto stage2 = [&](auto SAFE_c) {
        constexpr bool SAFE = decltype(SAFE_c)::value;
        const int tx = tid & 15, ty = tid >> 4;
        const int gi  = i0 + ty;
        const int gjb = j0 + 4 * tx;
        const int lr  = ty + 1;
        const int lc  = 4 * tx + 4;
        float4 v;
        float xA[6], xS[6], xN[4], r0C[5], r0N[4], r1C[5], r1S[4];
        xA[0] = sb[0][lr][lc - 1];
        v = *(const float4*)&sb[0][lr][lc]; xA[1]=v.x; xA[2]=v.y; xA[3]=v.z; xA[4]=v.w;
        xA[5] = sb[0][lr][lc + 4];
        xS[0] = sb[0][lr + 1][lc - 1];
        v = *(const float4*)&sb[0][lr + 1][lc]; xS[1]=v.x; xS[2]=v.y; xS[3]=v.z; xS[4]=v.w;
        xS[5] = sb[0][lr + 1][lc + 4];
        v = *(const float4*)&sb[0][lr - 1][lc]; xN[0]=v.x; xN[1]=v.y; xN[2]=v.z; xN[3]=v.w;
        r0C[0] = sb[1][lr][lc - 1];
        v = *(const float4*)&sb[1][lr][lc]; r0C[1]=v.x; r0C[2]=v.y; r0C[3]=v.z; r0C[4]=v.w;
        v = *(const float4*)&sb[1][lr - 1][lc]; r0N[0]=v.x; r0N[1]=v.y; r0N[2]=v.z; r0N[3]=v.w;
        r1C[0] = sb[2][lr][lc - 1];
        v = *(const float4*)&sb[2][lr][lc]; r1C[1]=v.x; r1C[2]=v.y; r1C[3]=v.z; r1C[4]=v.w;
        v = *(const float4*)&sb[2][lr + 1][lc]; r1S[0]=v.x; r1S[1]=v.y; r1S[2]=v.z; r1S[3]=v.w;

        const bool im0 = SAFE ? true : (gi > 0);
        const bool imH = SAFE ? true : (gi < H - 1);
        float un0[4], un1[4], un2[4], un3[4];
        #pragma unroll
        for (int e = 0; e < 4; ++e) {
            const int gj = gjb + e;
            const bool jm0 = SAFE ? true : (gj > 0);
            const bool jmW = SAFE ? true : (gj < W - 1);
            const float xC = xA[e + 1], xE = xA[e + 2], xW_ = xA[e];
            const float I0c = (imH ? xS[e + 1] - xC : 0.f) - r0C[e + 1];
            const float I0n = im0 ? (xC - xN[e] - r0N[e]) : 0.f;
            const float I0w = jm0 ? ((imH ? xS[e] - xW_ : 0.f) - r0C[e]) : 0.f;
            const float I1c = (jmW ? xE - xC : 0.f) - r1C[e + 1];
            const float I1w = jm0 ? (xC - xW_ - r1C[e]) : 0.f;
            const float I1s = imH ? ((jmW ? xS[e + 2] - xS[e + 1] : 0.f) - r1S[e]) : 0.f;
            const float g0 = I0c - I0n;
            const float g1 = jm0 ? (I0c - I0w) : 0.f;
            const float g2 = I1c - I1w;
            const float g3 = imH ? (I1s - I1c) : 0.f;
            const float up0 = cu0[e] + SIGMA * g0;
            const float up1 = cu1[e] + SIGMA * g1;
            const float up2 = cu2[e] + SIGMA * g2;
            const float up3 = cu3[e] + SIGMA * g3;
            const float ss  = up0 * up0 + up1 * up1 + up2 * up2 + up3 * up3;
            const float inv = fminf(LAM2 * rsqrtf(ss), 1.f);
            un0[e] = cu0[e] + RHO * (up0 * inv - cu0[e]);
            un1[e] = cu1[e] + RHO * (up1 * inv - cu1[e]);
            un2[e] = cu2[e] + RHO * (up2 * inv - cu2[e]);
            un3[e] = cu3[e] + RHO * (up3 * inv - cu3[e]);
        }
        const int p = cb + gi * W + gjb;
        if (MODE == 2) {
            #pragma unroll
            for (int e = 0; e < 4; ++e)
                *(float4*)(outp + 3 * CHW + 4 * (p + e)) =
                    make_float4(un0[e], un1[e], un2[e], un3[e]);
        } else {
            h4 o0, o1, o2, o3;
            #pragma unroll
            for (int e = 0; e < 4; ++e) {
                o0[e] = (f16)un0[e]; o1[e] = (f16)un1[e];
                o2[e] = (f16)un2[e]; o3[e] = (f16)un3[e];
            }
            *(h4*)(dstH + (HP_U + 0) * CHW + p) = o0;
            *(h4*)(dstH + (HP_U + 1) * CHW + p) = o1;
            *(h4*)(dstH + (HP_U + 2) * CHW + p) = o2;
            *(h4*)(dstH + (HP_U + 3) * CHW + p) = o3;
        }
    };

    if (tid < 128) {
        if (!edge) stage2(std::true_type{});
        else       stage2(std::false_type{});
    }
}

extern "C" void kernel_launch(void* const* d_in, const int* in_sizes, int n_in,
                              void* d_out, int out_size, void* d_ws, size_t ws_size,
                              hipStream_t stream) {
    const float* y = (const float*)d_in[0];
    float* out = (float*)d_out;

    // ws layout: x2 fp32 buf0 | x2 fp32 buf1 | h-buf0 (6*CHW f16) | h-buf1
    float* x0 = (float*)d_ws;
    float* x1 = x0 + CHW;
    f16*   h0 = (f16*)(x1 + CHW);
    f16*   h1 = h0 + 6 * CHW;

    dim3 blk(192, 1, 1);
    dim3 grd(W / TW, H / TH, C);    // (8, 64, 3) = 1536 blocks

    fused_it<0><<<grd, blk, 0, stream>>>(y, nullptr, nullptr, x0, h0, nullptr);
    for (int k = 2; k < N_IT; ++k) {
        const bool even = (k % 2 == 0);
        float* sx = even ? x0 : x1;  f16* sh = even ? h0 : h1;
        float* dx = even ? x1 : x0;  f16* dh = even ? h1 : h0;
        fused_it<1><<<grd, blk, 0, stream>>>(y, sx, sh, dx, dh, nullptr);
    }
    fused_it<2><<<grd, blk, 0, stream>>>(y, x0, h0, nullptr, nullptr, out);
}

// Round 9
// 335.245 us; speedup vs baseline: 1.2260x; 1.1445x over previous
//
#include <hip/hip_runtime.h>
#include <type_traits>

// TGV prox primal-dual, 30 iterations on (3,512,512) fp32.
// R9: PIXEL-INTERLEAVED STATE LAYOUT (single lever vs R8: instruction diet).
// Ladder: R4 bytes x0.6 -> -3.6%; R5 occ x2 -> -3.2%; R6 launches x0.53 -> 0%;
// R7 epochs/barriers halved -> 0%; R8 mask-free interior -> -6.6% (CONFIRMED:
// floor is instruction-stream bound). This round cuts the next-biggest
// instruction class: global-load issue + 64-bit address chains.
//  - u stored as 4xf16 PER PIXEL (8B): the 14 per-strip u-loads over 4 planes
//    collapse to 10 segment loads on 3 row bases (imm-offset addressing).
//  - r stored as (r0,r1) pairs: 2 loads -> 1, 2 stores -> 1.
//  - edge masking per SEGMENT (strips 4-aligned, W%4==0 => segments all-in or
//    all-out) instead of per element.
//  - same bytes, same fp16 roundings, same arithmetic order -> bit-identical.
// Frozen: x2 fp32 / state fp16 ping-pong, single barrier, block 192, rsqrt
// projections, 30 launches, SAFE/edge block split.
// R3: never grid.sync on this chip (~200us/iter).

#define H 512
#define W 512
#define C 3
#define HW (H * W)
#define CHW (C * H * W)
#define N_IT 30

#define TW 64
#define TH 8

#define TAU     0.01f
#define LAM2    0.15f
#define RHO     1.99f
#define SIGMA   1.3888888888888888f   /* 1/TAU/72 */
#define TL1     0.001f                /* TAU*LAM1 */
#define INV_1PT (1.0f / 1.01f)        /* 1/(1+TAU) */

// xbar/rbar planes rows -1..8 (10), cols lc = col+4 (col -4..67)
#define BROWS 10
#define BSTR  72

typedef _Float16 f16;
typedef __attribute__((ext_vector_type(4))) _Float16 h4;   //  8B
typedef __attribute__((ext_vector_type(8))) _Float16 h8;   // 16B

// h-buffer layout (f16 units): [0, 2*CHW) = r interleaved (r0,r1) per pixel;
//                              [2*CHW, 6*CHW) = u interleaved (u0..u3) per pixel.

template <int MODE> // 0 = first iter, 1 = middle, 2 = last (dst = d_out interleaved)
__global__ __launch_bounds__(192)
void fused_it(const float* __restrict__ y,
              const float* __restrict__ srcX,
              const f16*   __restrict__ srcH,
              float*       __restrict__ dstX,
              f16*         __restrict__ dstH,
              float*       __restrict__ outp)
{
    __shared__ float sb[3][BROWS][BSTR]; // 0=xbar 1=rbar0 2=rbar1

    const int tid = threadIdx.x;
    const int c   = blockIdx.z;
    const int i0  = blockIdx.y * TH;
    const int j0  = blockIdx.x * TW;
    const int cb  = c * HW;

    // block-uniform: all halo accesses in-image and all boundary conds true?
    const bool edge = (MODE == 0) ||
                      (blockIdx.x == 0) || (blockIdx.x == W / TW - 1) ||
                      (blockIdx.y == 0) || (blockIdx.y == H / TH - 1);

    const f16* rSrc = srcH;            // (r0,r1) pairs
    const f16* uSrc = srcH + 2 * CHW;  // (u0..u3) quads
    f16* rDst = dstH;
    f16* uDst = dstH ? dstH + 2 * CHW : nullptr;

    // center-u kept in registers for stage-2 (valid for interior threads)
    float cu0[4], cu1[4], cu2[4], cu3[4];

    // ---- stage 1: x/r prox on a strip of 4 positions; xbar/rbar -> LDS ----
    auto strip1 = [&](auto SAFE_c, int rr, int s, bool interior) {
        constexpr bool SAFE = decltype(SAFE_c)::value;
        const int gi  = i0 + rr;
        const int gjb = j0 + s;
        const int p   = cb + gi * W + gjb;

        const bool rowC  = SAFE || ((unsigned)gi < H);
        const bool cMain = SAFE || ((unsigned)gjb < W);  // covers gjb..gjb+3 (4-aligned)
        const bool okC   = rowC && cMain;

        float yv[4], x2c[4], r0c[4], r1c[4];
        if (okC) {
            *(float4*)yv = *(const float4*)(y + p);
        } else {
            yv[0] = yv[1] = yv[2] = yv[3] = 0.f;
        }
        if (MODE != 0) {
            if (okC) {
                *(float4*)x2c = *(const float4*)(srcX + p);
                const h8 rv = *(const h8*)(rSrc + 2 * p);
                #pragma unroll
                for (int e = 0; e < 4; ++e) {
                    r0c[e] = (float)rv[2 * e];
                    r1c[e] = (float)rv[2 * e + 1];
                }
            } else {
                #pragma unroll
                for (int e = 0; e < 4; ++e) { x2c[e] = 0.f; r0c[e] = 0.f; r1c[e] = 0.f; }
            }
        }

        float t0c[4], t1c[4], t0n[4], t1w[4];
        if (MODE == 0) {
            #pragma unroll
            for (int e = 0; e < 4; ++e) {
                x2c[e] = yv[e]; r0c[e] = 0.f; r1c[e] = 0.f;
                t0c[e] = t1c[e] = t0n[e] = t1w[e] = 0.f;
            }
            if (interior) {
                #pragma unroll
                for (int e = 0; e < 4; ++e) { cu0[e] = cu1[e] = cu2[e] = cu3[e] = 0.f; }
            }
        } else {
            const bool rowN = SAFE || ((unsigned)(gi - 1) < H);
            const bool rowS = SAFE || ((unsigned)(gi + 1) < H);
            const bool cm1  = SAFE || ((unsigned)(gjb - 1) < W);
            const bool c4   = SAFE || ((unsigned)(gjb + 4) < W);
            const int pN = p - W, pS = p + W;

            auto L4 = [&](int pp, bool ok) -> h4 {
                h4 z = {}; if (ok) z = *(const h4*)(uSrc + 4 * pp); return z;
            };
            auto L8 = [&](int pp, bool ok) -> h8 {
                h8 z = {}; if (ok) z = *(const h8*)(uSrc + 4 * pp); return z;
            };
            // 10 segment loads on 3 row bases (vs 14 loads over 4 planes before)
            const h4 nA = L4(pN - 1, rowN && cm1);
            const h8 nB = L8(pN,     rowN && cMain);
            const h8 nC = L8(pN + 2, rowN && cMain);
            const h4 nD = L4(pN + 4, rowN && c4);
            const h4 cA = L4(p - 1,  rowC && cm1);
            const h8 cB = L8(p,      okC);
            const h8 cC = L8(p + 2,  okC);
            const h4 cD = L4(p + 4,  rowC && c4);
            const h8 sB = L8(pS,     rowS && cMain);
            const h8 sC = L8(pS + 2, rowS && cMain);

            const float u0c[4] = {(float)cB[0], (float)cB[4], (float)cC[0], (float)cC[4]};
            const float u1c[5] = {(float)cB[1], (float)cB[5], (float)cC[1], (float)cC[5], (float)cD[1]};
            const float u2r[6] = {(float)cA[2], (float)cB[2], (float)cB[6], (float)cC[2], (float)cC[6], (float)cD[2]};
            const float u3c[5] = {(float)cA[3], (float)cB[3], (float)cB[7], (float)cC[3], (float)cC[7]};
            const float u0n[4] = {(float)nB[0], (float)nB[4], (float)nC[0], (float)nC[4]};
            const float u1n[5] = {(float)nB[1], (float)nB[5], (float)nC[1], (float)nC[5], (float)nD[1]};
            const float u3n[5] = {(float)nA[3], (float)nB[3], (float)nB[7], (float)nC[3], (float)nC[7]};
            const float u0s[4] = {(float)sB[0], (float)sB[4], (float)sC[0], (float)sC[4]};

            if constexpr (SAFE) {
                #pragma unroll
                for (int e = 0; e < 4; ++e) {
                    t0c[e] = TAU * (u0c[e] - u0s[e] + u1c[e] - u1c[e + 1]);
                    t1c[e] = TAU * (u2r[e + 1] - u2r[e + 2] + u3n[e + 1] - u3c[e + 1]);
                    t0n[e] = TAU * (u0n[e] - u0c[e] + u1n[e] - u1n[e + 1]);
                    t1w[e] = TAU * (u2r[e] - u2r[e + 1] + u3n[e] - u3c[e]);
                }
            } else {
                const bool im0 = gi > 0, imHl = gi < H - 1;
                #pragma unroll
                for (int e = 0; e < 4; ++e) {
                    const int gj = gjb + e;
                    const bool jm0 = gj > 0;
                    t0c[e] = TAU * (u0c[e] - u0s[e] + (jm0 ? u1c[e] : 0.f) - u1c[e + 1]);
                    t1c[e] = TAU * (u2r[e + 1] - u2r[e + 2] + u3n[e + 1] - (imHl ? u3c[e + 1] : 0.f));
                    t0n[e] = im0 ? TAU * (u0n[e] - u0c[e] + (jm0 ? u1n[e] : 0.f) - u1n[e + 1]) : 0.f;
                    t1w[e] = jm0 ? TAU * (u2r[e] - u2r[e + 1] + u3n[e] - (imHl ? u3c[e] : 0.f)) : 0.f;
                }
            }
            if (interior) {
                #pragma unroll
                for (int e = 0; e < 4; ++e) {
                    cu0[e] = u0c[e]; cu1[e] = u1c[e];
                    cu2[e] = u2r[e + 1]; cu3[e] = u3c[e + 1];
                }
            }
        }

        float xnew[4], rn0[4], rn1[4], xb[4], rb0[4], rb1[4];
        {
            const bool imH = SAFE ? true : (gi < H - 1);
            #pragma unroll
            for (int e = 0; e < 4; ++e) {
                const int gj = gjb + e;
                const bool jmW = SAFE ? true : (gj < W - 1);
                const float nT  = t0n[e] - (imH ? t0c[e] : 0.f) + t1w[e] - (jmW ? t1c[e] : 0.f);
                const float xv  = (x2c[e] - nT + TAU * yv[e]) * INV_1PT;
                xb[e] = 2.f * xv - x2c[e];
                const float rp0 = r0c[e] + t0c[e];
                const float rp1 = r1c[e] + t1c[e];
                const float ss  = rp0 * rp0 + rp1 * rp1;
                const float f   = 1.f - fminf(TL1 * rsqrtf(ss), 1.f);
                const float rv0 = rp0 * f, rv1 = rp1 * f;
                rb0[e]  = 2.f * rv0 - r0c[e];
                rb1[e]  = 2.f * rv1 - r1c[e];
                xnew[e] = x2c[e] + RHO * (xv - x2c[e]);
                rn0[e]  = r0c[e] + RHO * (rv0 - r0c[e]);
                rn1[e]  = r1c[e] + RHO * (rv1 - r1c[e]);
            }
        }
        *(float4*)&sb[0][rr + 1][s + 4] = *(float4*)xb;
        *(float4*)&sb[1][rr + 1][s + 4] = *(float4*)rb0;
        *(float4*)&sb[2][rr + 1][s + 4] = *(float4*)rb1;

        if (interior) {
            if (MODE == 2) {
                *(float4*)(outp + p) = *(float4*)xnew;
                *(float4*)(outp + CHW + 2 * p)     = make_float4(rn0[0], rn1[0], rn0[1], rn1[1]);
                *(float4*)(outp + CHW + 2 * p + 4) = make_float4(rn0[2], rn1[2], rn0[3], rn1[3]);
            } else {
                *(float4*)(dstX + p) = *(float4*)xnew;
                h8 hr;
                #pragma unroll
                for (int e = 0; e < 4; ++e) {
                    hr[2 * e]     = (f16)rn0[e];
                    hr[2 * e + 1] = (f16)rn1[e];
                }
                *(h8*)(rDst + 2 * p) = hr;   // 1 store (was 2)
            }
        }
    };

    auto ringmap = [&](int t, int& rr, int& s) {
        if (t < 18)      { rr = -1;      s = 4 * t - 4; }
        else if (t < 36) { rr = TH;      s = 4 * (t - 18) - 4; }
        else if (t < 44) { rr = t - 36;  s = -4; }
        else             { rr = t - 44;  s = TW; }
    };

    if (!edge) {
        if (tid < 128) {
            strip1(std::true_type{}, tid >> 4, 4 * (tid & 15), true);
        } else if (tid < 180) {
            int rr, s; ringmap(tid - 128, rr, s);
            strip1(std::true_type{}, rr, s, false);
        }
    } else {
        if (tid < 128) {
            strip1(std::false_type{}, tid >> 4, 4 * (tid & 15), true);
        } else if (tid < 180) {
            int rr, s; ringmap(tid - 128, rr, s);
            strip1(std::false_type{}, rr, s, false);
        }
    }
    __syncthreads(); // the ONLY barrier: xbar/rbar handoff

    // ---- stage 2: u prox on interior; u-old from registers ----
    auto stage2 = [&](auto SAFE_c) {
        constexpr bool SAFE = decltype(SAFE_c)::value;
        const int tx = tid & 15, ty = tid >> 4;
        const int gi  = i0 + ty;
        const int gjb = j0 + 4 * tx;
        const int lr  = ty + 1;
        const int lc  = 4 * tx + 4;
        float4 v;
        float xA[6], xS[6], xN[4], r0C[5], r0N[4], r1C[5], r1S[4];
        xA[0] = sb[0][lr][lc - 1];
        v = *(const float4*)&sb[0][lr][lc]; xA[1]=v.x; xA[2]=v.y; xA[3]=v.z; xA[4]=v.w;
        xA[5] = sb[0][lr][lc + 4];
        xS[0] = sb[0][lr + 1][lc - 1];
        v = *(const float4*)&sb[0][lr + 1][lc]; xS[1]=v.x; xS[2]=v.y; xS[3]=v.z; xS[4]=v.w;
        xS[5] = sb[0][lr + 1][lc + 4];
        v = *(const float4*)&sb[0][lr - 1][lc]; xN[0]=v.x; xN[1]=v.y; xN[2]=v.z; xN[3]=v.w;
        r0C[0] = sb[1][lr][lc - 1];
        v = *(const float4*)&sb[1][lr][lc]; r0C[1]=v.x; r0C[2]=v.y; r0C[3]=v.z; r0C[4]=v.w;
        v = *(const float4*)&sb[1][lr - 1][lc]; r0N[0]=v.x; r0N[1]=v.y; r0N[2]=v.z; r0N[3]=v.w;
        r1C[0] = sb[2][lr][lc - 1];
        v = *(const float4*)&sb[2][lr][lc]; r1C[1]=v.x; r1C[2]=v.y; r1C[3]=v.z; r1C[4]=v.w;
        v = *(const float4*)&sb[2][lr + 1][lc]; r1S[0]=v.x; r1S[1]=v.y; r1S[2]=v.z; r1S[3]=v.w;

        const bool im0 = SAFE ? true : (gi > 0);
        const bool imH = SAFE ? true : (gi < H - 1);
        float un0[4], un1[4], un2[4], un3[4];
        #pragma unroll
        for (int e = 0; e < 4; ++e) {
            const int gj = gjb + e;
            const bool jm0 = SAFE ? true : (gj > 0);
            const bool jmW = SAFE ? true : (gj < W - 1);
            const float xC = xA[e + 1], xE = xA[e + 2], xW_ = xA[e];
            const float I0c = (imH ? xS[e + 1] - xC : 0.f) - r0C[e + 1];
            const float I0n = im0 ? (xC - xN[e] - r0N[e]) : 0.f;
            const float I0w = jm0 ? ((imH ? xS[e] - xW_ : 0.f) - r0C[e]) : 0.f;
            const float I1c = (jmW ? xE - xC : 0.f) - r1C[e + 1];
            const float I1w = jm0 ? (xC - xW_ - r1C[e]) : 0.f;
            const float I1s = imH ? ((jmW ? xS[e + 2] - xS[e + 1] : 0.f) - r1S[e]) : 0.f;
            const float g0 = I0c - I0n;
            const float g1 = jm0 ? (I0c - I0w) : 0.f;
            const float g2 = I1c - I1w;
            const float g3 = imH ? (I1s - I1c) : 0.f;
            const float up0 = cu0[e] + SIGMA * g0;
            const float up1 = cu1[e] + SIGMA * g1;
            const float up2 = cu2[e] + SIGMA * g2;
            const float up3 = cu3[e] + SIGMA * g3;
            const float ss  = up0 * up0 + up1 * up1 + up2 * up2 + up3 * up3;
            const float inv = fminf(LAM2 * rsqrtf(ss), 1.f);
            un0[e] = cu0[e] + RHO * (up0 * inv - cu0[e]);
            un1[e] = cu1[e] + RHO * (up1 * inv - cu1[e]);
            un2[e] = cu2[e] + RHO * (up2 * inv - cu2[e]);
            un3[e] = cu3[e] + RHO * (up3 * inv - cu3[e]);
        }
        const int p = cb + gi * W + gjb;
        if (MODE == 2) {
            #pragma unroll
            for (int e = 0; e < 4; ++e)
                *(float4*)(outp + 3 * CHW + 4 * (p + e)) =
                    make_float4(un0[e], un1[e], un2[e], un3[e]);
        } else {
            // packed u store: 2 x 16B (was 4 x 8B over 4 planes)
            h8 w0, w1;
            #pragma unroll
            for (int e = 0; e < 2; ++e) {
                w0[4 * e + 0] = (f16)un0[e]; w0[4 * e + 1] = (f16)un1[e];
                w0[4 * e + 2] = (f16)un2[e]; w0[4 * e + 3] = (f16)un3[e];
            }
            #pragma unroll
            for (int e = 2; e < 4; ++e) {
                w1[4 * (e - 2) + 0] = (f16)un0[e]; w1[4 * (e - 2) + 1] = (f16)un1[e];
                w1[4 * (e - 2) + 2] = (f16)un2[e]; w1[4 * (e - 2) + 3] = (f16)un3[e];
            }
            *(h8*)(uDst + 4 * p)     = w0;
            *(h8*)(uDst + 4 * p + 8) = w1;
        }
    };

    if (tid < 128) {
        if (!edge) stage2(std::true_type{});
        else       stage2(std::false_type{});
    }
}

extern "C" void kernel_launch(void* const* d_in, const int* in_sizes, int n_in,
                              void* d_out, int out_size, void* d_ws, size_t ws_size,
                              hipStream_t stream) {
    const float* y = (const float*)d_in[0];
    float* out = (float*)d_out;

    // ws layout: x2 fp32 buf0 | x2 fp32 buf1 | h-buf0 (6*CHW f16) | h-buf1
    float* x0 = (float*)d_ws;
    float* x1 = x0 + CHW;
    f16*   h0 = (f16*)(x1 + CHW);
    f16*   h1 = h0 + 6 * CHW;

    dim3 blk(192, 1, 1);
    dim3 grd(W / TW, H / TH, C);    // (8, 64, 3) = 1536 blocks

    fused_it<0><<<grd, blk, 0, stream>>>(y, nullptr, nullptr, x0, h0, nullptr);
    for (int k = 2; k < N_IT; ++k) {
        const bool even = (k % 2 == 0);
        float* sx = even ? x0 : x1;  f16* sh = even ? h0 : h1;
        float* dx = even ? x1 : x0;  f16* dh = even ? h1 : h0;
        fused_it<1><<<grd, blk, 0, stream>>>(y, sx, sh, dx, dh, nullptr);
    }
    fused_it<2><<<grd, blk, 0, stream>>>(y, x0, h0, nullptr, nullptr, out);
}

// Round 10
// 331.763 us; speedup vs baseline: 1.2389x; 1.0105x over previous
//
#include <hip/hip_runtime.h>
#include <type_traits>

// TGV prox primal-dual, 30 iterations on (3,512,512) fp32.
// R10: TH 8->16 (halo-recompute 1.406x -> 1.266x) + stage-2 register reuse
// of own xbar/rbar (13 -> 10 ds_reads). Both bit-identical transforms.
// Ladder: R4 bytes x0.6 -> -3.6%; R5 occ x2 -> -3.2%; R6 launches x0.53 -> 0%;
// R7 epochs/barriers halved -> 0%; R8 mask-free interior -> -6.6%;
// R9 interleaved state (fewer loads + addr chains) -> -12.6%. CONFIRMED lever:
// instruction count / dependency chains. This round cuts redundant ring work
// (now that LDS is small, TH=16 keeps 18 waves/CU: 384-thr blocks x 768 = 3/CU)
// and the LDS round-trip for thread-own values.
// Frozen: x2 fp32 / state fp16 interleaved ping-pong, single barrier,
// concurrent ring, rsqrt projections, SAFE/edge block split, 30 launches.
// R3: never grid.sync on this chip (~200us/iter).

#define H 512
#define W 512
#define C 3
#define HW (H * W)
#define CHW (C * H * W)
#define N_IT 30

#define TW 64
#define TH 16

#define TAU     0.01f
#define LAM2    0.15f
#define RHO     1.99f
#define SIGMA   1.3888888888888888f   /* 1/TAU/72 */
#define TL1     0.001f                /* TAU*LAM1 */
#define INV_1PT (1.0f / 1.01f)        /* 1/(1+TAU) */

// xbar/rbar planes rows -1..16 (18), cols lc = col+4 (col -4..67)
#define BROWS 18
#define BSTR  72

typedef _Float16 f16;
typedef __attribute__((ext_vector_type(4))) _Float16 h4;   //  8B
typedef __attribute__((ext_vector_type(8))) _Float16 h8;   // 16B

// h-buffer layout (f16 units): [0, 2*CHW) = r interleaved (r0,r1) per pixel;
//                              [2*CHW, 6*CHW) = u interleaved (u0..u3) per pixel.

template <int MODE> // 0 = first iter, 1 = middle, 2 = last (dst = d_out interleaved)
__global__ __launch_bounds__(384)
void fused_it(const float* __restrict__ y,
              const float* __restrict__ srcX,
              const f16*   __restrict__ srcH,
              float*       __restrict__ dstX,
              f16*         __restrict__ dstH,
              float*       __restrict__ outp)
{
    __shared__ float sb[3][BROWS][BSTR]; // 0=xbar 1=rbar0 2=rbar1

    const int tid = threadIdx.x;
    const int c   = blockIdx.z;
    const int i0  = blockIdx.y * TH;
    const int j0  = blockIdx.x * TW;
    const int cb  = c * HW;

    // block-uniform: all halo accesses in-image and all boundary conds true?
    const bool edge = (MODE == 0) ||
                      (blockIdx.x == 0) || (blockIdx.x == W / TW - 1) ||
                      (blockIdx.y == 0) || (blockIdx.y == H / TH - 1);

    const f16* rSrc = srcH;            // (r0,r1) pairs
    const f16* uSrc = srcH + 2 * CHW;  // (u0..u3) quads
    f16* rDst = dstH;
    f16* uDst = dstH ? dstH + 2 * CHW : nullptr;

    // kept in registers across the barrier for stage-2 (interior threads)
    float cu0[4], cu1[4], cu2[4], cu3[4];          // center u (old)
    float xbO[4], rb0O[4], rb1O[4];                // own xbar/rbar

    // ---- stage 1: x/r prox on a strip of 4 positions; xbar/rbar -> LDS ----
    auto strip1 = [&](auto SAFE_c, int rr, int s, bool interior) {
        constexpr bool SAFE = decltype(SAFE_c)::value;
        const int gi  = i0 + rr;
        const int gjb = j0 + s;
        const int p   = cb + gi * W + gjb;

        const bool rowC  = SAFE || ((unsigned)gi < H);
        const bool cMain = SAFE || ((unsigned)gjb < W);  // covers gjb..gjb+3 (4-aligned)
        const bool okC   = rowC && cMain;

        float yv[4], x2c[4], r0c[4], r1c[4];
        if (okC) {
            *(float4*)yv = *(const float4*)(y + p);
        } else {
            yv[0] = yv[1] = yv[2] = yv[3] = 0.f;
        }
        if (MODE != 0) {
            if (okC) {
                *(float4*)x2c = *(const float4*)(srcX + p);
                const h8 rv = *(const h8*)(rSrc + 2 * p);
                #pragma unroll
                for (int e = 0; e < 4; ++e) {
                    r0c[e] = (float)rv[2 * e];
                    r1c[e] = (float)rv[2 * e + 1];
                }
            } else {
                #pragma unroll
                for (int e = 0; e < 4; ++e) { x2c[e] = 0.f; r0c[e] = 0.f; r1c[e] = 0.f; }
            }
        }

        float t0c[4], t1c[4], t0n[4], t1w[4];
        if (MODE == 0) {
            #pragma unroll
            for (int e = 0; e < 4; ++e) {
                x2c[e] = yv[e]; r0c[e] = 0.f; r1c[e] = 0.f;
                t0c[e] = t1c[e] = t0n[e] = t1w[e] = 0.f;
            }
            if (interior) {
                #pragma unroll
                for (int e = 0; e < 4; ++e) { cu0[e] = cu1[e] = cu2[e] = cu3[e] = 0.f; }
            }
        } else {
            const bool rowN = SAFE || ((unsigned)(gi - 1) < H);
            const bool rowS = SAFE || ((unsigned)(gi + 1) < H);
            const bool cm1  = SAFE || ((unsigned)(gjb - 1) < W);
            const bool c4   = SAFE || ((unsigned)(gjb + 4) < W);
            const int pN = p - W, pS = p + W;

            auto L4 = [&](int pp, bool ok) -> h4 {
                h4 z = {}; if (ok) z = *(const h4*)(uSrc + 4 * pp); return z;
            };
            auto L8 = [&](int pp, bool ok) -> h8 {
                h8 z = {}; if (ok) z = *(const h8*)(uSrc + 4 * pp); return z;
            };
            // 10 segment loads on 3 row bases
            const h4 nA = L4(pN - 1, rowN && cm1);
            const h8 nB = L8(pN,     rowN && cMain);
            const h8 nC = L8(pN + 2, rowN && cMain);
            const h4 nD = L4(pN + 4, rowN && c4);
            const h4 cA = L4(p - 1,  rowC && cm1);
            const h8 cB = L8(p,      okC);
            const h8 cC = L8(p + 2,  okC);
            const h4 cD = L4(p + 4,  rowC && c4);
            const h8 sB = L8(pS,     rowS && cMain);
            const h8 sC = L8(pS + 2, rowS && cMain);

            const float u0c[4] = {(float)cB[0], (float)cB[4], (float)cC[0], (float)cC[4]};
            const float u1c[5] = {(float)cB[1], (float)cB[5], (float)cC[1], (float)cC[5], (float)cD[1]};
            const float u2r[6] = {(float)cA[2], (float)cB[2], (float)cB[6], (float)cC[2], (float)cC[6], (float)cD[2]};
            const float u3c[5] = {(float)cA[3], (float)cB[3], (float)cB[7], (float)cC[3], (float)cC[7]};
            const float u0n[4] = {(float)nB[0], (float)nB[4], (float)nC[0], (float)nC[4]};
            const float u1n[5] = {(float)nB[1], (float)nB[5], (float)nC[1], (float)nC[5], (float)nD[1]};
            const float u3n[5] = {(float)nA[3], (float)nB[3], (float)nB[7], (float)nC[3], (float)nC[7]};
            const float u0s[4] = {(float)sB[0], (float)sB[4], (float)sC[0], (float)sC[4]};

            if constexpr (SAFE) {
                #pragma unroll
                for (int e = 0; e < 4; ++e) {
                    t0c[e] = TAU * (u0c[e] - u0s[e] + u1c[e] - u1c[e + 1]);
                    t1c[e] = TAU * (u2r[e + 1] - u2r[e + 2] + u3n[e + 1] - u3c[e + 1]);
                    t0n[e] = TAU * (u0n[e] - u0c[e] + u1n[e] - u1n[e + 1]);
                    t1w[e] = TAU * (u2r[e] - u2r[e + 1] + u3n[e] - u3c[e]);
                }
            } else {
                const bool im0 = gi > 0, imHl = gi < H - 1;
                #pragma unroll
                for (int e = 0; e < 4; ++e) {
                    const int gj = gjb + e;
                    const bool jm0 = gj > 0;
                    t0c[e] = TAU * (u0c[e] - u0s[e] + (jm0 ? u1c[e] : 0.f) - u1c[e + 1]);
                    t1c[e] = TAU * (u2r[e + 1] - u2r[e + 2] + u3n[e + 1] - (imHl ? u3c[e + 1] : 0.f));
                    t0n[e] = im0 ? TAU * (u0n[e] - u0c[e] + (jm0 ? u1n[e] : 0.f) - u1n[e + 1]) : 0.f;
                    t1w[e] = jm0 ? TAU * (u2r[e] - u2r[e + 1] + u3n[e] - (imHl ? u3c[e] : 0.f)) : 0.f;
                }
            }
            if (interior) {
                #pragma unroll
                for (int e = 0; e < 4; ++e) {
                    cu0[e] = u0c[e]; cu1[e] = u1c[e];
                    cu2[e] = u2r[e + 1]; cu3[e] = u3c[e + 1];
                }
            }
        }

        float xnew[4], rn0[4], rn1[4], xb[4], rb0[4], rb1[4];
        {
            const bool imH = SAFE ? true : (gi < H - 1);
            #pragma unroll
            for (int e = 0; e < 4; ++e) {
                const int gj = gjb + e;
                const bool jmW = SAFE ? true : (gj < W - 1);
                const float nT  = t0n[e] - (imH ? t0c[e] : 0.f) + t1w[e] - (jmW ? t1c[e] : 0.f);
                const float xv  = (x2c[e] - nT + TAU * yv[e]) * INV_1PT;
                xb[e] = 2.f * xv - x2c[e];
                const float rp0 = r0c[e] + t0c[e];
                const float rp1 = r1c[e] + t1c[e];
                const float ss  = rp0 * rp0 + rp1 * rp1;
                const float f   = 1.f - fminf(TL1 * rsqrtf(ss), 1.f);
                const float rv0 = rp0 * f, rv1 = rp1 * f;
                rb0[e]  = 2.f * rv0 - r0c[e];
                rb1[e]  = 2.f * rv1 - r1c[e];
                xnew[e] = x2c[e] + RHO * (xv - x2c[e]);
                rn0[e]  = r0c[e] + RHO * (rv0 - r0c[e]);
                rn1[e]  = r1c[e] + RHO * (rv1 - r1c[e]);
            }
        }
        *(float4*)&sb[0][rr + 1][s + 4] = *(float4*)xb;
        *(float4*)&sb[1][rr + 1][s + 4] = *(float4*)rb0;
        *(float4*)&sb[2][rr + 1][s + 4] = *(float4*)rb1;

        if (interior) {
            // keep own xbar/rbar in registers for stage-2 (skip 3 ds_reads)
            #pragma unroll
            for (int e = 0; e < 4; ++e) {
                xbO[e] = xb[e]; rb0O[e] = rb0[e]; rb1O[e] = rb1[e];
            }
            if (MODE == 2) {
                *(float4*)(outp + p) = *(float4*)xnew;
                *(float4*)(outp + CHW + 2 * p)     = make_float4(rn0[0], rn1[0], rn0[1], rn1[1]);
                *(float4*)(outp + CHW + 2 * p + 4) = make_float4(rn0[2], rn1[2], rn0[3], rn1[3]);
            } else {
                *(float4*)(dstX + p) = *(float4*)xnew;
                h8 hr;
                #pragma unroll
                for (int e = 0; e < 4; ++e) {
                    hr[2 * e]     = (f16)rn0[e];
                    hr[2 * e + 1] = (f16)rn1[e];
                }
                *(h8*)(rDst + 2 * p) = hr;
            }
        }
    };

    auto ringmap = [&](int t, int& rr, int& s) {
        if (t < 18)      { rr = -1;      s = 4 * t - 4; }
        else if (t < 36) { rr = TH;      s = 4 * (t - 18) - 4; }
        else if (t < 36 + TH) { rr = t - 36;      s = -4; }
        else                  { rr = t - 36 - TH; s = TW; }
    };

    // stage 1: threads 0-255 interior (16 rows x 16 strips), threads 256-323
    // the 68 ring strips, all concurrent (different waves).
    if (!edge) {
        if (tid < 256) {
            strip1(std::true_type{}, tid >> 4, 4 * (tid & 15), true);
        } else if (tid < 256 + 36 + 2 * TH) {
            int rr, s; ringmap(tid - 256, rr, s);
            strip1(std::true_type{}, rr, s, false);
        }
    } else {
        if (tid < 256) {
            strip1(std::false_type{}, tid >> 4, 4 * (tid & 15), true);
        } else if (tid < 256 + 36 + 2 * TH) {
            int rr, s; ringmap(tid - 256, rr, s);
            strip1(std::false_type{}, rr, s, false);
        }
    }
    __syncthreads(); // the ONLY barrier: xbar/rbar handoff

    // ---- stage 2: u prox on interior; own xbar/rbar + center-u from regs ----
    auto stage2 = [&](auto SAFE_c) {
        constexpr bool SAFE = decltype(SAFE_c)::value;
        const int tx = tid & 15, ty = tid >> 4;
        const int gi  = i0 + ty;
        const int gjb = j0 + 4 * tx;
        const int lr  = ty + 1;
        const int lc  = 4 * tx + 4;
        float4 v;
        float xA[6], xS[6], xN[4], r0C[5], r0N[4], r1C[5], r1S[4];
        // true neighbor data from LDS (10 reads); own values from registers
        xA[0] = sb[0][lr][lc - 1];
        xA[1] = xbO[0]; xA[2] = xbO[1]; xA[3] = xbO[2]; xA[4] = xbO[3];
        xA[5] = sb[0][lr][lc + 4];
        xS[0] = sb[0][lr + 1][lc - 1];
        v = *(const float4*)&sb[0][lr + 1][lc]; xS[1]=v.x; xS[2]=v.y; xS[3]=v.z; xS[4]=v.w;
        xS[5] = sb[0][lr + 1][lc + 4];
        v = *(const float4*)&sb[0][lr - 1][lc]; xN[0]=v.x; xN[1]=v.y; xN[2]=v.z; xN[3]=v.w;
        r0C[0] = sb[1][lr][lc - 1];
        r0C[1] = rb0O[0]; r0C[2] = rb0O[1]; r0C[3] = rb0O[2]; r0C[4] = rb0O[3];
        v = *(const float4*)&sb[1][lr - 1][lc]; r0N[0]=v.x; r0N[1]=v.y; r0N[2]=v.z; r0N[3]=v.w;
        r1C[0] = sb[2][lr][lc - 1];
        r1C[1] = rb1O[0]; r1C[2] = rb1O[1]; r1C[3] = rb1O[2]; r1C[4] = rb1O[3];
        v = *(const float4*)&sb[2][lr + 1][lc]; r1S[0]=v.x; r1S[1]=v.y; r1S[2]=v.z; r1S[3]=v.w;

        const bool im0 = SAFE ? true : (gi > 0);
        const bool imH = SAFE ? true : (gi < H - 1);
        float un0[4], un1[4], un2[4], un3[4];
        #pragma unroll
        for (int e = 0; e < 4; ++e) {
            const int gj = gjb + e;
            const bool jm0 = SAFE ? true : (gj > 0);
            const bool jmW = SAFE ? true : (gj < W - 1);
            const float xC = xA[e + 1], xE = xA[e + 2], xW_ = xA[e];
            const float I0c = (imH ? xS[e + 1] - xC : 0.f) - r0C[e + 1];
            const float I0n = im0 ? (xC - xN[e] - r0N[e]) : 0.f;
            const float I0w = jm0 ? ((imH ? xS[e] - xW_ : 0.f) - r0C[e]) : 0.f;
            const float I1c = (jmW ? xE - xC : 0.f) - r1C[e + 1];
            const float I1w = jm0 ? (xC - xW_ - r1C[e]) : 0.f;
            const float I1s = imH ? ((jmW ? xS[e + 2] - xS[e + 1] : 0.f) - r1S[e]) : 0.f;
            const float g0 = I0c - I0n;
            const float g1 = jm0 ? (I0c - I0w) : 0.f;
            const float g2 = I1c - I1w;
            const float g3 = imH ? (I1s - I1c) : 0.f;
            const float up0 = cu0[e] + SIGMA * g0;
            const float up1 = cu1[e] + SIGMA * g1;
            const float up2 = cu2[e] + SIGMA * g2;
            const float up3 = cu3[e] + SIGMA * g3;
            const float ss  = up0 * up0 + up1 * up1 + up2 * up2 + up3 * up3;
            const float inv = fminf(LAM2 * rsqrtf(ss), 1.f);
            un0[e] = cu0[e] + RHO * (up0 * inv - cu0[e]);
            un1[e] = cu1[e] + RHO * (up1 * inv - cu1[e]);
            un2[e] = cu2[e] + RHO * (up2 * inv - cu2[e]);
            un3[e] = cu3[e] + RHO * (up3 * inv - cu3[e]);
        }
        const int p = cb + gi * W + gjb;
        if (MODE == 2) {
            #pragma unroll
            for (int e = 0; e < 4; ++e)
                *(float4*)(outp + 3 * CHW + 4 * (p + e)) =
                    make_float4(un0[e], un1[e], un2[e], un3[e]);
        } else {
            h8 w0, w1;
            #pragma unroll
            for (int e = 0; e < 2; ++e) {
                w0[4 * e + 0] = (f16)un0[e]; w0[4 * e + 1] = (f16)un1[e];
                w0[4 * e + 2] = (f16)un2[e]; w0[4 * e + 3] = (f16)un3[e];
            }
            #pragma unroll
            for (int e = 2; e < 4; ++e) {
                w1[4 * (e - 2) + 0] = (f16)un0[e]; w1[4 * (e - 2) + 1] = (f16)un1[e];
                w1[4 * (e - 2) + 2] = (f16)un2[e]; w1[4 * (e - 2) + 3] = (f16)un3[e];
            }
            *(h8*)(uDst + 4 * p)     = w0;
            *(h8*)(uDst + 4 * p + 8) = w1;
        }
    };

    if (tid < 256) {
        if (!edge) stage2(std::true_type{});
        else       stage2(std::false_type{});
    }
}

extern "C" void kernel_launch(void* const* d_in, const int* in_sizes, int n_in,
                              void* d_out, int out_size, void* d_ws, size_t ws_size,
                              hipStream_t stream) {
    const float* y = (const float*)d_in[0];
    float* out = (float*)d_out;

    // ws layout: x2 fp32 buf0 | x2 fp32 buf1 | h-buf0 (6*CHW f16) | h-buf1
    float* x0 = (float*)d_ws;
    float* x1 = x0 + CHW;
    f16*   h0 = (f16*)(x1 + CHW);
    f16*   h1 = h0 + 6 * CHW;

    dim3 blk(384, 1, 1);
    dim3 grd(W / TW, H / TH, C);    // (8, 32, 3) = 768 blocks = 3/CU, 18 waves/CU

    fused_it<0><<<grd, blk, 0, stream>>>(y, nullptr, nullptr, x0, h0, nullptr);
    for (int k = 2; k < N_IT; ++k) {
        const bool even = (k % 2 == 0);
        float* sx = even ? x0 : x1;  f16* sh = even ? h0 : h1;
        float* dx = even ? x1 : x0;  f16* dh = even ? h1 : h0;
        fused_it<1><<<grd, blk, 0, stream>>>(y, sx, sh, dx, dh, nullptr);
    }
    fused_it<2><<<grd, blk, 0, stream>>>(y, x0, h0, nullptr, nullptr, out);
}